// Round 5
// baseline (607.024 us; speedup 1.0000x reference)
//
#include <hip/hip_runtime.h>

typedef __bf16 bf16_t;
typedef __bf16 bf16x4 __attribute__((ext_vector_type(4)));
typedef __bf16 bf16x8 __attribute__((ext_vector_type(8)));
typedef float f32x4 __attribute__((ext_vector_type(4)));

#define NB 4        // batch
#define SS 2048     // seq
#define DM 1024     // d_model
#define NH 16       // heads
#define DK 64       // d_kv
#define MM (NB*SS)  // 8192 rows
#define LOG2E 1.44269504f

// ---------------- convert H (fp32) -> bf16 ----------------
__global__ __launch_bounds__(256) void k_convert(const float* __restrict__ in,
                                                 bf16_t* __restrict__ out, int n4) {
  int i = blockIdx.x * 256 + threadIdx.x;
  if (i < n4) {
    float4 v = ((const float4*)in)[i];
    bf16x4 o = {(bf16_t)v.x, (bf16_t)v.y, (bf16_t)v.z, (bf16_t)v.w};
    *(bf16x4*)(out + 4 * (size_t)i) = o;
  }
}

// ---------------- transpose-convert weights: Wt[n][k] = bf16(W[k][n]) ----------------
__global__ __launch_bounds__(256) void k_transpose(
    const float* __restrict__ W0, const float* __restrict__ W1,
    const float* __restrict__ W2, const float* __restrict__ W3,
    bf16_t* __restrict__ T0, bf16_t* __restrict__ T1,
    bf16_t* __restrict__ T2, bf16_t* __restrict__ T3) {
  __shared__ float t[64][65];
  const float* W = blockIdx.z == 0 ? W0 : blockIdx.z == 1 ? W1 : blockIdx.z == 2 ? W2 : W3;
  bf16_t* T = blockIdx.z == 0 ? T0 : blockIdx.z == 1 ? T1 : blockIdx.z == 2 ? T2 : T3;
  int k0 = blockIdx.y * 64, n0 = blockIdx.x * 64;
  int tid = threadIdx.x;
#pragma unroll
  for (int i = 0; i < 16; i++) {
    int idx = tid + i * 256; int r = idx >> 6, c = idx & 63;
    t[r][c] = W[(size_t)(k0 + r) * DM + n0 + c];
  }
  __syncthreads();
#pragma unroll
  for (int i = 0; i < 16; i++) {
    int idx = tid + i * 256; int r = idx >> 6, c = idx & 63;
    T[(size_t)(n0 + r) * DM + k0 + c] = (bf16_t)t[c][r];
  }
}

// ---------------- T5 bias table, pre-scaled by log2(e): biasT[h][rel+2047] ----------------
__global__ __launch_bounds__(256) void k_bias(const float* __restrict__ rel_emb,
                                              float* __restrict__ biasT) {
  int t = blockIdx.x * 256 + threadIdx.x;
  if (t >= 2 * SS - 1) return;
  int rel = t - (SS - 1);      // rel = j - i (memory - context)
  int n = -rel;                // reference: n = -relative_position
  int ret = 0;
  if (n < 0) { ret = 16; n = -n; }
  int bucket;
  if (n < 8) bucket = n;
  else {
    int v = 8 + (int)(logf((float)n * 0.125f) * (8.0f / logf(16.0f)));
    bucket = v < 15 ? v : 15;
  }
  bucket += ret;
#pragma unroll
  for (int h = 0; h < NH; h++)
    biasT[h * (2 * SS - 1) + t] = rel_emb[bucket * NH + h] * LOG2E;
}

// ---------------- async 16B global -> LDS (lane i deposits at lds_base + 16*i) -------------
__device__ __forceinline__ void gld16(const bf16_t* g, bf16_t* l) {
  __builtin_amdgcn_global_load_lds(
      (const __attribute__((address_space(1))) unsigned int*)g,
      (__attribute__((address_space(3))) unsigned int*)l, 16, 0, 0);
}

// ---------------- m97-style GEMM mainloop: C[128x128] = A[MxK] * Bt[NxK]^T ----------------
__device__ __forceinline__ void gemm_tile(const bf16_t* __restrict__ A,
                                          const bf16_t* __restrict__ Bt, const int K,
                                          const int m0, const int n0,
                                          bf16_t* As, bf16_t* Bs, f32x4 (&acc)[4][4]) {
  const int tid = threadIdx.x;
  const int lane = tid & 63, wave = tid >> 6;
  const int l15 = lane & 15, quad = lane >> 4;
  const int wm = (wave >> 1) * 64, wn = (wave & 1) * 64;
  const int wwu = __builtin_amdgcn_readfirstlane(wave);
  const f32x4 z4 = {0.f, 0.f, 0.f, 0.f};
#pragma unroll
  for (int i = 0; i < 4; i++)
#pragma unroll
    for (int j = 0; j < 4; j++) acc[i][j] = z4;

  const int rr = lane >> 2;
  const int cc = (lane & 3) * 8;
  for (int k0 = 0; k0 < K; k0 += 32) {
    __syncthreads();
    gld16(A + (size_t)(m0 + wwu * 32 + rr) * K + k0 + cc,       As + wwu * 1024);
    gld16(A + (size_t)(m0 + wwu * 32 + 16 + rr) * K + k0 + cc,  As + wwu * 1024 + 512);
    gld16(Bt + (size_t)(n0 + wwu * 32 + rr) * K + k0 + cc,      Bs + wwu * 1024);
    gld16(Bt + (size_t)(n0 + wwu * 32 + 16 + rr) * K + k0 + cc, Bs + wwu * 1024 + 512);
    __syncthreads();
    bf16x8 af[4], bfr[4];
#pragma unroll
    for (int i = 0; i < 4; i++) {
      af[i]  = *(const bf16x8*)(As + (wm + i * 16 + l15) * 32 + quad * 8);
      bfr[i] = *(const bf16x8*)(Bs + (wn + i * 16 + l15) * 32 + quad * 8);
    }
#pragma unroll
    for (int i = 0; i < 4; i++)
#pragma unroll
      for (int j = 0; j < 4; j++)
        acc[i][j] = __builtin_amdgcn_mfma_f32_16x16x32_bf16(af[i], bfr[j], acc[i][j], 0, 0, 0);
  }
}

// ---------------- QKV projection: Q scaled by log2e; Q,K [bh][s][d]; V panel-tiled ----------
// V layout: Vt[bh][panel=s/32][d][s%32]  -> a 32-key V^T tile is one contiguous 8KB block.
__global__ __launch_bounds__(256) void k_gemm_qkv(
    const bf16_t* __restrict__ A, const bf16_t* __restrict__ Wqt,
    const bf16_t* __restrict__ Wkt, const bf16_t* __restrict__ Wvt,
    bf16_t* __restrict__ Q, bf16_t* __restrict__ Ko, bf16_t* __restrict__ Vt) {
  __shared__ bf16_t As[128 * 32];
  __shared__ bf16_t Bs[128 * 32];
  const int which = blockIdx.z;
  const bf16_t* Bt = which == 0 ? Wqt : (which == 1 ? Wkt : Wvt);
  const int m0 = blockIdx.y * 128, n0 = blockIdx.x * 128;
  f32x4 acc[4][4];
  gemm_tile(A, Bt, DM, m0, n0, As, Bs, acc);

  const int tid = threadIdx.x;
  const int lane = tid & 63, wave = tid >> 6;
  const int l15 = lane & 15, quad = lane >> 4;
  const int wm = (wave >> 1) * 64, wn = (wave & 1) * 64;

  if (which < 2) {
    bf16_t* dst = which == 0 ? Q : Ko;
    const float qs = which == 0 ? LOG2E : 1.0f;
#pragma unroll
    for (int i = 0; i < 4; i++)
#pragma unroll
      for (int j = 0; j < 4; j++)
#pragma unroll
        for (int r = 0; r < 4; r++) {
          int m = m0 + wm + i * 16 + quad * 4 + r;
          int n = n0 + wn + j * 16 + l15;
          int b = m >> 11, s = m & (SS - 1);
          int h = n >> 6, d = n & 63;
          dst[(((size_t)(b * NH + h)) * SS + s) * DK + d] = (bf16_t)(acc[i][j][r] * qs);
        }
  } else {
#pragma unroll
    for (int i = 0; i < 4; i++)
#pragma unroll
      for (int j = 0; j < 4; j++) {
        int m = m0 + wm + i * 16 + quad * 4;   // 4 consecutive s (4-aligned, same 32-panel)
        int n = n0 + wn + j * 16 + l15;
        int b = m >> 11, s = m & (SS - 1);
        int h = n >> 6, d = n & 63;
        int p = s >> 5, off = s & 31;
        bf16x4 pk = {(bf16_t)acc[i][j][0], (bf16_t)acc[i][j][1],
                     (bf16_t)acc[i][j][2], (bf16_t)acc[i][j][3]};
        *(bf16x4*)(&Vt[(((size_t)((b * NH + h) * 64 + p)) * DK + d) * 32 + off]) = pk;
      }
  }
}

// ---------------- flash attention: LDS-staged, wave-specialized, bias-banded --------------
// T5 bucket saturates for |j-i| >= 91 -> bias is a per-head CONSTANT except when
// j0 - it0 in [-128, 192] (6 of 32 iterations). Constant iterations splat Bpos/Bneg
// into the MFMA C operand (no LDS gathers); band iterations gather from a 4KB window.
__global__ __launch_bounds__(256, 4) void k_attn(const bf16_t* __restrict__ Qg,
                                                 const bf16_t* __restrict__ Kg,
                                                 const bf16_t* __restrict__ Vt,
                                                 const float* __restrict__ biasT,
                                                 bf16_t* __restrict__ ctx) {
  const int bh = blockIdx.y;
  const int b = bh >> 4, h = bh & 15;
  const int it0 = blockIdx.x * 128;
  const bf16_t* Qp = Qg + ((size_t)bh * SS + it0) * DK;
  const bf16_t* Kp = Kg + (size_t)bh * SS * DK;
  const bf16_t* VtP = Vt + (size_t)bh * 64 * DK * 32;  // [panel][d][32]
  const float* biasH = biasT + h * (2 * SS - 1);

  __shared__ bf16_t KV[2][2][8][512];     // 32 KB staging; reused as fp32 O-reduce buffer
  __shared__ float bias2[512][2];         // diag-band window: bias2[w] = {B(w-256),B(w-255)}
  __shared__ float OsumS[2][4][16];       // per (qh, mi, qrow) partial denominators

  const int tid = threadIdx.x;
  const int lane = tid & 63, wave = tid >> 6;
  const int l15 = lane & 15, quad = lane >> 4;
  const int kh = wave & 1, qh = wave >> 1;
  const int kperm = 8 * (l15 >> 2) + (l15 & 3);

  // band window fill: rel = w - 256 in [-256, 256)
  for (int w = tid; w < 512; w += 256) {
    int g = w - 256 + (SS - 1);
    bias2[w][0] = biasH[g];
    bias2[w][1] = biasH[g + 1];
  }
  const float Bpos = biasH[(SS - 1) + 1024];   // rel >= 128: saturated bucket 31
  const float Bneg = biasH[(SS - 1) - 1024];   // rel <= -128: saturated bucket 15

  // stage one 64-key tile into buffer `buf` (16 gld16 split 4-per-wave)
  auto stage = [&](int buf, int j0) {
    {  // K: global rows permuted to fragment order
      int t = wave;
      const bf16_t* g = Kp + (size_t)(j0 + 32 * (t >> 1) + 4 * (t & 1) + kperm) * DK + quad * 8;
      gld16(g,      &KV[buf][0][t * 2 + 0][0]);
      gld16(g + 32, &KV[buf][0][t * 2 + 1][0]);
    }
    {  // V: panels are contiguous 8KB
      int c = wave >> 1, nib = (wave & 1) * 2;
      const bf16_t* g = VtP + ((size_t)((j0 >> 5) + c) * DK + nib * 16 + l15) * 32 + quad * 8;
      gld16(g,           &KV[buf][1][c * 4 + nib][0]);
      gld16(g + 16 * 32, &KV[buf][1][c * 4 + nib + 1][0]);
    }
  };

  // Q fragments (persistent): qrows 64*qh + mi*16 + l15
  bf16x8 qf[4][2];
#pragma unroll
  for (int mi = 0; mi < 4; mi++) {
    const bf16_t* qr = Qp + (size_t)(64 * qh + mi * 16 + l15) * DK + quad * 8;
    qf[mi][0] = *(const bf16x8*)qr;
    qf[mi][1] = *(const bf16x8*)(qr + 32);
  }

  f32x4 accO[4][4], accS[4];
  const f32x4 z4 = {0.f, 0.f, 0.f, 0.f};
#pragma unroll
  for (int mi = 0; mi < 4; mi++) {
    accS[mi] = z4;
#pragma unroll
    for (int ni = 0; ni < 4; ni++) accO[mi][ni] = z4;
  }
  const bf16_t one = (bf16_t)1.0f;
  const bf16x8 ones = {one, one, one, one, one, one, one, one};

  stage(0, 0);
  // band-gather fragment base (w for reg r=0, tile0): rel0 + 256
  const int wb0 = 32 * kh + 8 * quad - 64 * qh - l15 - it0 + 256;

  for (int it = 0; it < 32; ++it) {
    const int cb = it & 1;
    __syncthreads();                       // drains prev staging (vmcnt) + orders buffers
    if (it < 31) stage(cb ^ 1, (it + 1) * 64);

    // fragment loads: lane-linear ds_read_b128, conflict-free
    bf16x8 kf[2][2], vf[4];
#pragma unroll
    for (int t = 0; t < 2; t++)
#pragma unroll
      for (int hf = 0; hf < 2; hf++)
        kf[t][hf] = *(const bf16x8*)&KV[cb][0][(2 * kh + t) * 2 + hf][lane * 8];
#pragma unroll
    for (int ni = 0; ni < 4; ni++)
      vf[ni] = *(const bf16x8*)&KV[cb][1][kh * 4 + ni][lane * 8];

    const int diff = it * 64 - it0;               // j0 - it0 (block-uniform)
    const bool band = (diff >= -128) && (diff < 256);
    const float cconst = diff >= 256 ? Bpos : Bneg;
    const f32x4 csplat = {cconst, cconst, cconst, cconst};
    const int jb = it * 64 + wb0;

#pragma unroll
    for (int mi = 0; mi < 4; mi++) {
      f32x4 c0, c1;
      if (band) {
        const int w = jb - mi * 16;
        float2 a0 = *(const float2*)bias2[w],     b0 = *(const float2*)bias2[w + 2];
        float2 a1 = *(const float2*)bias2[w + 4], b1 = *(const float2*)bias2[w + 6];
        c0 = f32x4{a0.x, a0.y, b0.x, b0.y};
        c1 = f32x4{a1.x, a1.y, b1.x, b1.y};
      } else {
        c0 = csplat;
        c1 = csplat;
      }
      // S^T tiles (bias pre-added via C operand)
      f32x4 s0 = __builtin_amdgcn_mfma_f32_16x16x32_bf16(
          kf[0][1], qf[mi][1],
          __builtin_amdgcn_mfma_f32_16x16x32_bf16(kf[0][0], qf[mi][0], c0, 0, 0, 0), 0, 0, 0);
      f32x4 s1 = __builtin_amdgcn_mfma_f32_16x16x32_bf16(
          kf[1][1], qf[mi][1],
          __builtin_amdgcn_mfma_f32_16x16x32_bf16(kf[1][0], qf[mi][0], c1, 0, 0, 0), 0, 0, 0);
      // exp2 numerator (raw v_exp_f32) -> P^T B-fragment
      bf16x8 pf = {(bf16_t)__builtin_amdgcn_exp2f(s0[0]), (bf16_t)__builtin_amdgcn_exp2f(s0[1]),
                   (bf16_t)__builtin_amdgcn_exp2f(s0[2]), (bf16_t)__builtin_amdgcn_exp2f(s0[3]),
                   (bf16_t)__builtin_amdgcn_exp2f(s1[0]), (bf16_t)__builtin_amdgcn_exp2f(s1[1]),
                   (bf16_t)__builtin_amdgcn_exp2f(s1[2]), (bf16_t)__builtin_amdgcn_exp2f(s1[3])};
      // PV + denominator (ones-MFMA)
#pragma unroll
      for (int ni = 0; ni < 4; ni++)
        accO[mi][ni] = __builtin_amdgcn_mfma_f32_16x16x32_bf16(vf[ni], pf, accO[mi][ni], 0, 0, 0);
      accS[mi] = __builtin_amdgcn_mfma_f32_16x16x32_bf16(ones, pf, accS[mi], 0, 0, 0);
    }
  }

  // cross-wave combine over key-halves (kh=1 dumps partials; kh=0 reduces + writes out)
  __syncthreads();
  f32x4* Ored = (f32x4*)&KV[0][0][0][0];  // 32 KB, staging done
  if (kh) {
#pragma unroll
    for (int mi = 0; mi < 4; mi++) {
#pragma unroll
      for (int ni = 0; ni < 4; ni++)
        Ored[((qh * 4 + mi) * 4 + ni) * 64 + lane] = accO[mi][ni];
      if (quad == 0) OsumS[qh][mi][l15] = accS[mi][0];
    }
  }
  __syncthreads();
  if (!kh) {
#pragma unroll
    for (int mi = 0; mi < 4; mi++) {
      float l = accS[mi][0] + OsumS[qh][mi][l15];
      float inv = 1.0f / l;
      int srow = it0 + 64 * qh + mi * 16 + l15;
#pragma unroll
      for (int ni = 0; ni < 4; ni++) {
        f32x4 o = accO[mi][ni] + Ored[((qh * 4 + mi) * 4 + ni) * 64 + lane];
        bf16x4 pk = {(bf16_t)(o[0] * inv), (bf16_t)(o[1] * inv),
                     (bf16_t)(o[2] * inv), (bf16_t)(o[3] * inv)};
        *(bf16x4*)(&ctx[((size_t)(b * SS + srow)) * DM + h * DK + ni * 16 + quad * 4]) = pk;
      }
    }
  }
}

// ---------------- output projection: out = ctx @ Wo (fp32 out) ----------------
__global__ __launch_bounds__(256) void k_gemm_out(const bf16_t* __restrict__ A,
                                                  const bf16_t* __restrict__ Wot,
                                                  float* __restrict__ out) {
  __shared__ bf16_t As[128 * 32];
  __shared__ bf16_t Bs[128 * 32];
  const int m0 = blockIdx.y * 128, n0 = blockIdx.x * 128;
  f32x4 acc[4][4];
  gemm_tile(A, Wot, DM, m0, n0, As, Bs, acc);

  const int tid = threadIdx.x;
  const int lane = tid & 63, wave = tid >> 6;
  const int l15 = lane & 15, quad = lane >> 4;
  const int wm = (wave >> 1) * 64, wn = (wave & 1) * 64;
#pragma unroll
  for (int i = 0; i < 4; i++)
#pragma unroll
    for (int j = 0; j < 4; j++)
#pragma unroll
      for (int r = 0; r < 4; r++) {
        int m = m0 + wm + i * 16 + quad * 4 + r;
        int n = n0 + wn + j * 16 + l15;
        out[(size_t)m * DM + n] = acc[i][j][r];
      }
}

extern "C" void kernel_launch(void* const* d_in, const int* in_sizes, int n_in,
                              void* d_out, int out_size, void* d_ws, size_t ws_size,
                              hipStream_t stream) {
  (void)in_sizes; (void)n_in; (void)out_size; (void)ws_size;
  const float* H  = (const float*)d_in[0];
  const float* Wq = (const float*)d_in[1];
  const float* Wk = (const float*)d_in[2];
  const float* Wv = (const float*)d_in[3];
  const float* Wo = (const float*)d_in[4];
  const float* rel = (const float*)d_in[5];
  float* out = (float*)d_out;

  char* w = (char*)d_ws;
  bf16_t* Hbf = (bf16_t*)w; w += (size_t)MM * DM * 2;
  bf16_t* Wqt = (bf16_t*)w; w += (size_t)DM * DM * 2;
  bf16_t* Wkt = (bf16_t*)w; w += (size_t)DM * DM * 2;
  bf16_t* Wvt = (bf16_t*)w; w += (size_t)DM * DM * 2;
  bf16_t* Wot = (bf16_t*)w; w += (size_t)DM * DM * 2;
  bf16_t* Q   = (bf16_t*)w; w += (size_t)MM * DM * 2;
  bf16_t* K   = (bf16_t*)w; w += (size_t)MM * DM * 2;
  bf16_t* Vt  = (bf16_t*)w; w += (size_t)MM * DM * 2;
  bf16_t* CTX = (bf16_t*)w; w += (size_t)MM * DM * 2;
  float* biasT = (float*)w;  // NH * 4095 floats

  k_convert<<<MM * DM / 4 / 256, 256, 0, stream>>>(H, Hbf, MM * DM / 4);
  k_transpose<<<dim3(16, 16, 4), 256, 0, stream>>>(Wq, Wk, Wv, Wo, Wqt, Wkt, Wvt, Wot);
  k_bias<<<(2 * SS - 1 + 255) / 256, 256, 0, stream>>>(rel, biasT);
  k_gemm_qkv<<<dim3(DM / 128, MM / 128, 3), 256, 0, stream>>>(Hbf, Wqt, Wkt, Wvt, Q, K, Vt);
  k_attn<<<dim3(SS / 128, NB * NH), 256, 0, stream>>>(Q, K, Vt, biasT, CTX);
  k_gemm_out<<<dim3(DM / 128, MM / 128), 256, 0, stream>>>(CTX, Wot, out);
}

// Round 6
// 273.055 us; speedup vs baseline: 2.2231x; 2.2231x over previous
//
#include <hip/hip_runtime.h>

typedef __bf16 bf16_t;
typedef __bf16 bf16x4 __attribute__((ext_vector_type(4)));
typedef __bf16 bf16x8 __attribute__((ext_vector_type(8)));
typedef float f32x4 __attribute__((ext_vector_type(4)));

#define NB 4        // batch
#define SS 2048     // seq
#define DM 1024     // d_model
#define NH 16       // heads
#define DK 64       // d_kv
#define MM (NB*SS)  // 8192 rows
#define LOG2E 1.44269504f

// ---------------- convert H (fp32) -> bf16 ----------------
__global__ __launch_bounds__(256) void k_convert(const float* __restrict__ in,
                                                 bf16_t* __restrict__ out, int n4) {
  int i = blockIdx.x * 256 + threadIdx.x;
  if (i < n4) {
    float4 v = ((const float4*)in)[i];
    bf16x4 o = {(bf16_t)v.x, (bf16_t)v.y, (bf16_t)v.z, (bf16_t)v.w};
    *(bf16x4*)(out + 4 * (size_t)i) = o;
  }
}

// ---------------- transpose-convert weights: Wt[n][k] = bf16(W[k][n]) ----------------
__global__ __launch_bounds__(256) void k_transpose(
    const float* __restrict__ W0, const float* __restrict__ W1,
    const float* __restrict__ W2, const float* __restrict__ W3,
    bf16_t* __restrict__ T0, bf16_t* __restrict__ T1,
    bf16_t* __restrict__ T2, bf16_t* __restrict__ T3) {
  __shared__ float t[64][65];
  const float* W = blockIdx.z == 0 ? W0 : blockIdx.z == 1 ? W1 : blockIdx.z == 2 ? W2 : W3;
  bf16_t* T = blockIdx.z == 0 ? T0 : blockIdx.z == 1 ? T1 : blockIdx.z == 2 ? T2 : T3;
  int k0 = blockIdx.y * 64, n0 = blockIdx.x * 64;
  int tid = threadIdx.x;
#pragma unroll
  for (int i = 0; i < 16; i++) {
    int idx = tid + i * 256; int r = idx >> 6, c = idx & 63;
    t[r][c] = W[(size_t)(k0 + r) * DM + n0 + c];
  }
  __syncthreads();
#pragma unroll
  for (int i = 0; i < 16; i++) {
    int idx = tid + i * 256; int r = idx >> 6, c = idx & 63;
    T[(size_t)(n0 + r) * DM + k0 + c] = (bf16_t)t[c][r];
  }
}

// ---------------- T5 bias table, pre-scaled by log2(e): biasT[h][rel+2047] ----------------
__global__ __launch_bounds__(256) void k_bias(const float* __restrict__ rel_emb,
                                              float* __restrict__ biasT) {
  int t = blockIdx.x * 256 + threadIdx.x;
  if (t >= 2 * SS - 1) return;
  int rel = t - (SS - 1);      // rel = j - i (memory - context)
  int n = -rel;                // reference: n = -relative_position
  int ret = 0;
  if (n < 0) { ret = 16; n = -n; }
  int bucket;
  if (n < 8) bucket = n;
  else {
    int v = 8 + (int)(logf((float)n * 0.125f) * (8.0f / logf(16.0f)));
    bucket = v < 15 ? v : 15;
  }
  bucket += ret;
#pragma unroll
  for (int h = 0; h < NH; h++)
    biasT[h * (2 * SS - 1) + t] = rel_emb[bucket * NH + h] * LOG2E;
}

// ---------------- async 16B global -> LDS (lane i deposits at lds_base + 16*i) -------------
__device__ __forceinline__ void gld16(const bf16_t* g, bf16_t* l) {
  __builtin_amdgcn_global_load_lds(
      (const __attribute__((address_space(1))) unsigned int*)g,
      (__attribute__((address_space(3))) unsigned int*)l, 16, 0, 0);
}

// ---------------- m97-style GEMM mainloop: C[128x128] = A[MxK] * Bt[NxK]^T ----------------
__device__ __forceinline__ void gemm_tile(const bf16_t* __restrict__ A,
                                          const bf16_t* __restrict__ Bt, const int K,
                                          const int m0, const int n0,
                                          bf16_t* As, bf16_t* Bs, f32x4 (&acc)[4][4]) {
  const int tid = threadIdx.x;
  const int lane = tid & 63, wave = tid >> 6;
  const int l15 = lane & 15, quad = lane >> 4;
  const int wm = (wave >> 1) * 64, wn = (wave & 1) * 64;
  const int wwu = __builtin_amdgcn_readfirstlane(wave);
  const f32x4 z4 = {0.f, 0.f, 0.f, 0.f};
#pragma unroll
  for (int i = 0; i < 4; i++)
#pragma unroll
    for (int j = 0; j < 4; j++) acc[i][j] = z4;

  const int rr = lane >> 2;
  const int cc = (lane & 3) * 8;
  for (int k0 = 0; k0 < K; k0 += 32) {
    __syncthreads();
    gld16(A + (size_t)(m0 + wwu * 32 + rr) * K + k0 + cc,       As + wwu * 1024);
    gld16(A + (size_t)(m0 + wwu * 32 + 16 + rr) * K + k0 + cc,  As + wwu * 1024 + 512);
    gld16(Bt + (size_t)(n0 + wwu * 32 + rr) * K + k0 + cc,      Bs + wwu * 1024);
    gld16(Bt + (size_t)(n0 + wwu * 32 + 16 + rr) * K + k0 + cc, Bs + wwu * 1024 + 512);
    __syncthreads();
    bf16x8 af[4], bfr[4];
#pragma unroll
    for (int i = 0; i < 4; i++) {
      af[i]  = *(const bf16x8*)(As + (wm + i * 16 + l15) * 32 + quad * 8);
      bfr[i] = *(const bf16x8*)(Bs + (wn + i * 16 + l15) * 32 + quad * 8);
    }
#pragma unroll
    for (int i = 0; i < 4; i++)
#pragma unroll
      for (int j = 0; j < 4; j++)
        acc[i][j] = __builtin_amdgcn_mfma_f32_16x16x32_bf16(af[i], bfr[j], acc[i][j], 0, 0, 0);
  }
}

// ---------------- QKV projection ----------------
// Q: row-major [bh][s][d], scaled by log2e.
// K, V: FRAGMENT-MAJOR layout: [bh][T=s/64][slot 0..7][lane 0..63][j 0..7] (slot = 1KB).
//   K slot = 4*((s>>5)&1) + 2*((s>>2)&1) + (d>>5); lane = ((d>>3)&3)*16 + 4*((s>>3)&3) + (s&3); j = d&7
//   V slot = 4*((s>>5)&1) + (d>>4);                lane = ((s>>3)&3)*16 + (d&15);              j = s&7
// These are exactly the MFMA fragments k_attn consumes (key-permuted S^T scheme), so the
// attention loop reads lane-linear contiguous 16B/lane -- no LDS staging needed.
__global__ __launch_bounds__(256) void k_gemm_qkv(
    const bf16_t* __restrict__ A, const bf16_t* __restrict__ Wqt,
    const bf16_t* __restrict__ Wkt, const bf16_t* __restrict__ Wvt,
    bf16_t* __restrict__ Q, bf16_t* __restrict__ Kf, bf16_t* __restrict__ Vf) {
  __shared__ bf16_t As[128 * 32];
  __shared__ bf16_t Bs[128 * 32];
  const int which = blockIdx.z;
  const bf16_t* Bt = which == 0 ? Wqt : (which == 1 ? Wkt : Wvt);
  const int m0 = blockIdx.y * 128, n0 = blockIdx.x * 128;
  f32x4 acc[4][4];
  gemm_tile(A, Bt, DM, m0, n0, As, Bs, acc);

  const int tid = threadIdx.x;
  const int lane = tid & 63, wave = tid >> 6;
  const int l15 = lane & 15, quad = lane >> 4;
  const int wm = (wave >> 1) * 64, wn = (wave & 1) * 64;

  if (which == 0) {
#pragma unroll
    for (int i = 0; i < 4; i++)
#pragma unroll
      for (int j = 0; j < 4; j++)
#pragma unroll
        for (int r = 0; r < 4; r++) {
          int m = m0 + wm + i * 16 + quad * 4 + r;
          int n = n0 + wn + j * 16 + l15;
          int b = m >> 11, s = m & (SS - 1);
          int h = n >> 6, d = n & 63;
          Q[(((size_t)(b * NH + h)) * SS + s) * DK + d] = (bf16_t)(acc[i][j][r] * LOG2E);
        }
  } else if (which == 1) {
#pragma unroll
    for (int i = 0; i < 4; i++)
#pragma unroll
      for (int j = 0; j < 4; j++)
#pragma unroll
        for (int r = 0; r < 4; r++) {
          int m = m0 + wm + i * 16 + quad * 4 + r;
          int n = n0 + wn + j * 16 + l15;
          int b = m >> 11, s = m & (SS - 1);
          int h = n >> 6, d = n & 63;
          int slot = 4 * ((s >> 5) & 1) + 2 * ((s >> 2) & 1) + (d >> 5);
          int fl = ((d >> 3) & 3) * 16 + 4 * ((s >> 3) & 3) + (s & 3);
          Kf[(((size_t)(b * NH + h) * 32 + (s >> 6)) * 8 + slot) * 512 + fl * 8 + (d & 7)] =
              (bf16_t)acc[i][j][r];
        }
  } else {
#pragma unroll
    for (int i = 0; i < 4; i++)
#pragma unroll
      for (int j = 0; j < 4; j++) {
        int m = m0 + wm + i * 16 + quad * 4;   // 4 consecutive s, 4-aligned
        int n = n0 + wn + j * 16 + l15;
        int b = m >> 11, s = m & (SS - 1);
        int h = n >> 6, d = n & 63;
        int slot = 4 * ((s >> 5) & 1) + (d >> 4);
        int fl = ((s >> 3) & 3) * 16 + (d & 15);
        bf16x4 pk = {(bf16_t)acc[i][j][0], (bf16_t)acc[i][j][1],
                     (bf16_t)acc[i][j][2], (bf16_t)acc[i][j][3]};
        *(bf16x4*)(&Vf[(((size_t)(b * NH + h) * 32 + (s >> 6)) * 8 + slot) * 512 +
                       fl * 8 + (s & 7)]) = pk;
      }
  }
}

// ---------------- flash attention: barrier-free loop, direct fragment loads ---------------
// Wave (qh, kh) owns 64 q-rows x 32 keys of each 64-key tile. K/V fragments stream
// global->VGPR (contiguous lane-linear 16B/lane), register double-buffered one tile ahead.
// Bias: saturated per-head constant except 6/32 diagonal-band iterations (4KB LDS window).
__global__ __launch_bounds__(256, 2) void k_attn(const bf16_t* __restrict__ Qg,
                                                 const bf16_t* __restrict__ Kf,
                                                 const bf16_t* __restrict__ Vf,
                                                 const float* __restrict__ biasT,
                                                 bf16_t* __restrict__ ctx) {
  const int bh = blockIdx.y;
  const int b = bh >> 4, h = bh & 15;
  const int it0 = blockIdx.x * 128;
  const bf16_t* Qp = Qg + ((size_t)bh * SS + it0) * DK;
  const float* biasH = biasT + h * (2 * SS - 1);

  __shared__ float bias2[512][2];         // diag-band: bias2[w] = {B(w-256), B(w-255)}
  __shared__ float OsumS[2][4][16];       // per (qh, mi, qrow) partial denominators
  __shared__ f32x4 Ored[2 * 4 * 4 * 64];  // 32 KB cross-wave O partials

  const int tid = threadIdx.x;
  const int lane = tid & 63, wave = tid >> 6;
  const int l15 = lane & 15, quad = lane >> 4;
  const int kh = wave & 1, qh = wave >> 1;

  // band window fill: rel = w - 256 in [-256, 256)
  for (int w = tid; w < 512; w += 256) {
    int g = w - 256 + (SS - 1);
    bias2[w][0] = biasH[g];
    bias2[w][1] = biasH[g + 1];
  }
  const float Bpos = biasH[(SS - 1) + 1024];   // rel >= 128: saturated bucket 31
  const float Bneg = biasH[(SS - 1) - 1024];   // rel <= -128: saturated bucket 15

  // per-wave fragment stream bases (lane-linear 16B)
  const bf16_t* KfB = Kf + (size_t)bh * 32 * 4096 + lane * 8;
  const bf16_t* VfB = Vf + (size_t)bh * 32 * 4096 + lane * 8;
  auto loadfrag = [&](int it, bf16x8 (&kf)[2][2], bf16x8 (&vf)[4]) {
    const bf16_t* kb = KfB + (size_t)it * 4096;
#pragma unroll
    for (int t = 0; t < 2; t++)
#pragma unroll
      for (int hf = 0; hf < 2; hf++)
        kf[t][hf] = *(const bf16x8*)(kb + ((2 * kh + t) * 2 + hf) * 512);
    const bf16_t* vb = VfB + (size_t)it * 4096;
#pragma unroll
    for (int ni = 0; ni < 4; ni++)
      vf[ni] = *(const bf16x8*)(vb + (kh * 4 + ni) * 512);
  };

  // Q fragments (persistent): qrows 64*qh + mi*16 + l15
  bf16x8 qf[4][2];
#pragma unroll
  for (int mi = 0; mi < 4; mi++) {
    const bf16_t* qr = Qp + (size_t)(64 * qh + mi * 16 + l15) * DK + quad * 8;
    qf[mi][0] = *(const bf16x8*)qr;
    qf[mi][1] = *(const bf16x8*)(qr + 32);
  }

  f32x4 accO[4][4], accS[4];
  const f32x4 z4 = {0.f, 0.f, 0.f, 0.f};
#pragma unroll
  for (int mi = 0; mi < 4; mi++) {
    accS[mi] = z4;
#pragma unroll
    for (int ni = 0; ni < 4; ni++) accO[mi][ni] = z4;
  }
  const bf16_t one = (bf16_t)1.0f;
  const bf16x8 ones = {one, one, one, one, one, one, one, one};

  // band-gather fragment base (w for reg r=0, tile0): rel0 + 256
  const int wb0 = 32 * kh + 8 * quad - 64 * qh - l15 - it0 + 256;

  auto body = [&](int it, bf16x8 (&kf)[2][2], bf16x8 (&vf)[4]) {
    const int diff = it * 64 - it0;               // j0 - it0 (block-uniform)
    const bool band = (diff >= -128) && (diff < 256);
    const float cconst = diff >= 256 ? Bpos : Bneg;
    const f32x4 csplat = {cconst, cconst, cconst, cconst};
    const int jb = it * 64 + wb0;
#pragma unroll
    for (int mi = 0; mi < 4; mi++) {
      f32x4 c0, c1;
      if (band) {
        const int w = jb - mi * 16;
        float2 a0 = *(const float2*)bias2[w],     b0 = *(const float2*)bias2[w + 2];
        float2 a1 = *(const float2*)bias2[w + 4], b1 = *(const float2*)bias2[w + 6];
        c0 = f32x4{a0.x, a0.y, b0.x, b0.y};
        c1 = f32x4{a1.x, a1.y, b1.x, b1.y};
      } else {
        c0 = csplat;
        c1 = csplat;
      }
      f32x4 s0 = __builtin_amdgcn_mfma_f32_16x16x32_bf16(
          kf[0][1], qf[mi][1],
          __builtin_amdgcn_mfma_f32_16x16x32_bf16(kf[0][0], qf[mi][0], c0, 0, 0, 0), 0, 0, 0);
      f32x4 s1 = __builtin_amdgcn_mfma_f32_16x16x32_bf16(
          kf[1][1], qf[mi][1],
          __builtin_amdgcn_mfma_f32_16x16x32_bf16(kf[1][0], qf[mi][0], c1, 0, 0, 0), 0, 0, 0);
      bf16x8 pf = {(bf16_t)__builtin_amdgcn_exp2f(s0[0]), (bf16_t)__builtin_amdgcn_exp2f(s0[1]),
                   (bf16_t)__builtin_amdgcn_exp2f(s0[2]), (bf16_t)__builtin_amdgcn_exp2f(s0[3]),
                   (bf16_t)__builtin_amdgcn_exp2f(s1[0]), (bf16_t)__builtin_amdgcn_exp2f(s1[1]),
                   (bf16_t)__builtin_amdgcn_exp2f(s1[2]), (bf16_t)__builtin_amdgcn_exp2f(s1[3])};
#pragma unroll
      for (int ni = 0; ni < 4; ni++)
        accO[mi][ni] = __builtin_amdgcn_mfma_f32_16x16x32_bf16(vf[ni], pf, accO[mi][ni], 0, 0, 0);
      accS[mi] = __builtin_amdgcn_mfma_f32_16x16x32_bf16(ones, pf, accS[mi], 0, 0, 0);
    }
  };

  bf16x8 kfA[2][2], vfA[4], kfB[2][2], vfB[4];
  loadfrag(0, kfA, vfA);
  __syncthreads();  // bias2 ready (only barrier before epilogue)

  for (int it = 0; it < 32; it += 2) {
    loadfrag(it + 1, kfB, vfB);
    body(it, kfA, vfA);
    if (it + 2 < 32) loadfrag(it + 2, kfA, vfA);
    body(it + 1, kfB, vfB);
  }

  // cross-wave combine over key-halves (kh=1 dumps partials; kh=0 reduces + writes out)
  __syncthreads();
  if (kh) {
#pragma unroll
    for (int mi = 0; mi < 4; mi++) {
#pragma unroll
      for (int ni = 0; ni < 4; ni++)
        Ored[((qh * 4 + mi) * 4 + ni) * 64 + lane] = accO[mi][ni];
      if (quad == 0) OsumS[qh][mi][l15] = accS[mi][0];
    }
  }
  __syncthreads();
  if (!kh) {
#pragma unroll
    for (int mi = 0; mi < 4; mi++) {
      float l = accS[mi][0] + OsumS[qh][mi][l15];
      float inv = 1.0f / l;
      int srow = it0 + 64 * qh + mi * 16 + l15;
#pragma unroll
      for (int ni = 0; ni < 4; ni++) {
        f32x4 o = accO[mi][ni] + Ored[((qh * 4 + mi) * 4 + ni) * 64 + lane];
        bf16x4 pk = {(bf16_t)(o[0] * inv), (bf16_t)(o[1] * inv),
                     (bf16_t)(o[2] * inv), (bf16_t)(o[3] * inv)};
        *(bf16x4*)(&ctx[((size_t)(b * SS + srow)) * DM + h * DK + ni * 16 + quad * 4]) = pk;
      }
    }
  }
}

// ---------------- output projection: out = ctx @ Wo (fp32 out) ----------------
__global__ __launch_bounds__(256) void k_gemm_out(const bf16_t* __restrict__ A,
                                                  const bf16_t* __restrict__ Wot,
                                                  float* __restrict__ out) {
  __shared__ bf16_t As[128 * 32];
  __shared__ bf16_t Bs[128 * 32];
  const int m0 = blockIdx.y * 128, n0 = blockIdx.x * 128;
  f32x4 acc[4][4];
  gemm_tile(A, Wot, DM, m0, n0, As, Bs, acc);

  const int tid = threadIdx.x;
  const int lane = tid & 63, wave = tid >> 6;
  const int l15 = lane & 15, quad = lane >> 4;
  const int wm = (wave >> 1) * 64, wn = (wave & 1) * 64;
#pragma unroll
  for (int i = 0; i < 4; i++)
#pragma unroll
    for (int j = 0; j < 4; j++)
#pragma unroll
      for (int r = 0; r < 4; r++) {
        int m = m0 + wm + i * 16 + quad * 4 + r;
        int n = n0 + wn + j * 16 + l15;
        out[(size_t)m * DM + n] = acc[i][j][r];
      }
}

extern "C" void kernel_launch(void* const* d_in, const int* in_sizes, int n_in,
                              void* d_out, int out_size, void* d_ws, size_t ws_size,
                              hipStream_t stream) {
  (void)in_sizes; (void)n_in; (void)out_size; (void)ws_size;
  const float* H  = (const float*)d_in[0];
  const float* Wq = (const float*)d_in[1];
  const float* Wk = (const float*)d_in[2];
  const float* Wv = (const float*)d_in[3];
  const float* Wo = (const float*)d_in[4];
  const float* rel = (const float*)d_in[5];
  float* out = (float*)d_out;

  char* w = (char*)d_ws;
  bf16_t* Hbf = (bf16_t*)w; w += (size_t)MM * DM * 2;
  bf16_t* Wqt = (bf16_t*)w; w += (size_t)DM * DM * 2;
  bf16_t* Wkt = (bf16_t*)w; w += (size_t)DM * DM * 2;
  bf16_t* Wvt = (bf16_t*)w; w += (size_t)DM * DM * 2;
  bf16_t* Wot = (bf16_t*)w; w += (size_t)DM * DM * 2;
  bf16_t* Q   = (bf16_t*)w; w += (size_t)MM * DM * 2;
  bf16_t* Kf  = (bf16_t*)w; w += (size_t)MM * DM * 2;
  bf16_t* Vf  = (bf16_t*)w; w += (size_t)MM * DM * 2;
  bf16_t* CTX = (bf16_t*)w; w += (size_t)MM * DM * 2;
  float* biasT = (float*)w;  // NH * 4095 floats

  k_convert<<<MM * DM / 4 / 256, 256, 0, stream>>>(H, Hbf, MM * DM / 4);
  k_transpose<<<dim3(16, 16, 4), 256, 0, stream>>>(Wq, Wk, Wv, Wo, Wqt, Wkt, Wvt, Wot);
  k_bias<<<(2 * SS - 1 + 255) / 256, 256, 0, stream>>>(rel, biasT);
  k_gemm_qkv<<<dim3(DM / 128, MM / 128, 3), 256, 0, stream>>>(Hbf, Wqt, Wkt, Wvt, Q, Kf, Vf);
  k_attn<<<dim3(SS / 128, NB * NH), 256, 0, stream>>>(Q, Kf, Vf, biasT, CTX);
  k_gemm_out<<<dim3(DM / 128, MM / 128), 256, 0, stream>>>(CTX, Wot, out);
}

// Round 7
// 261.498 us; speedup vs baseline: 2.3213x; 1.0442x over previous
//
#include <hip/hip_runtime.h>

typedef __bf16 bf16_t;
typedef __bf16 bf16x4 __attribute__((ext_vector_type(4)));
typedef __bf16 bf16x8 __attribute__((ext_vector_type(8)));
typedef float f32x4 __attribute__((ext_vector_type(4)));

#define NB 4        // batch
#define SS 2048     // seq
#define DM 1024     // d_model
#define NH 16       // heads
#define DK 64       // d_kv
#define MM (NB*SS)  // 8192 rows
#define LOG2E 1.44269504f

// ---------------- fused prep: convert H, transpose weights, bias table ----------------
// blocks [0,8192): H fp32 -> bf16 (float4/lane)
// blocks [8192,9216): 64x64 transpose-convert tiles of the 4 weight matrices
// blocks [9216,9232): T5 bias table biasT[h][rel+2047], pre-scaled by log2(e)
__global__ __launch_bounds__(256) void k_prep(
    const float* __restrict__ H, bf16_t* __restrict__ Hbf,
    const float* __restrict__ W0, const float* __restrict__ W1,
    const float* __restrict__ W2, const float* __restrict__ W3,
    bf16_t* __restrict__ T0, bf16_t* __restrict__ T1,
    bf16_t* __restrict__ T2, bf16_t* __restrict__ T3,
    const float* __restrict__ rel_emb, float* __restrict__ biasT) {
  __shared__ float t[64][65];
  const int blk = blockIdx.x, tid = threadIdx.x;
  if (blk < 8192) {
    int i = blk * 256 + tid;
    float4 v = ((const float4*)H)[i];
    bf16x4 o = {(bf16_t)v.x, (bf16_t)v.y, (bf16_t)v.z, (bf16_t)v.w};
    *(bf16x4*)(Hbf + 4 * (size_t)i) = o;
  } else if (blk < 9216) {
    int tt = blk - 8192;
    int which = tt >> 8, rem = tt & 255;
    int k0 = (rem >> 4) * 64, n0 = (rem & 15) * 64;
    const float* W = which == 0 ? W0 : which == 1 ? W1 : which == 2 ? W2 : W3;
    bf16_t* T = which == 0 ? T0 : which == 1 ? T1 : which == 2 ? T2 : T3;
#pragma unroll
    for (int i = 0; i < 16; i++) {
      int idx = tid + i * 256; int r = idx >> 6, c = idx & 63;
      t[r][c] = W[(size_t)(k0 + r) * DM + n0 + c];
    }
    __syncthreads();
#pragma unroll
    for (int i = 0; i < 16; i++) {
      int idx = tid + i * 256; int r = idx >> 6, c = idx & 63;
      T[(size_t)(n0 + r) * DM + k0 + c] = (bf16_t)t[c][r];
    }
  } else {
    int tt = (blk - 9216) * 256 + tid;
    if (tt < 2 * SS - 1) {
      int rel = tt - (SS - 1);     // rel = j - i
      int n = -rel;
      int ret = 0;
      if (n < 0) { ret = 16; n = -n; }
      int bucket;
      if (n < 8) bucket = n;
      else {
        int v = 8 + (int)(logf((float)n * 0.125f) * (8.0f / logf(16.0f)));
        bucket = v < 15 ? v : 15;
      }
      bucket += ret;
#pragma unroll
      for (int h = 0; h < NH; h++)
        biasT[h * (2 * SS - 1) + tt] = rel_emb[bucket * NH + h] * LOG2E;
    }
  }
}

// ---------------- async 16B global -> LDS (lane i deposits at lds_base + 16*i) -------------
__device__ __forceinline__ void gld16(const bf16_t* g, bf16_t* l) {
  __builtin_amdgcn_global_load_lds(
      (const __attribute__((address_space(1))) unsigned int*)g,
      (__attribute__((address_space(3))) unsigned int*)l, 16, 0, 0);
}

// ---------------- m97-style GEMM mainloop: C[128x128] = A[MxK] * Bt[NxK]^T ----------------
__device__ __forceinline__ void gemm_tile(const bf16_t* __restrict__ A,
                                          const bf16_t* __restrict__ Bt, const int K,
                                          const int m0, const int n0,
                                          bf16_t* As, bf16_t* Bs, f32x4 (&acc)[4][4]) {
  const int tid = threadIdx.x;
  const int lane = tid & 63, wave = tid >> 6;
  const int l15 = lane & 15, quad = lane >> 4;
  const int wm = (wave >> 1) * 64, wn = (wave & 1) * 64;
  const int wwu = __builtin_amdgcn_readfirstlane(wave);
  const f32x4 z4 = {0.f, 0.f, 0.f, 0.f};
#pragma unroll
  for (int i = 0; i < 4; i++)
#pragma unroll
    for (int j = 0; j < 4; j++) acc[i][j] = z4;

  const int rr = lane >> 2;
  const int cc = (lane & 3) * 8;
  for (int k0 = 0; k0 < K; k0 += 32) {
    __syncthreads();
    gld16(A + (size_t)(m0 + wwu * 32 + rr) * K + k0 + cc,       As + wwu * 1024);
    gld16(A + (size_t)(m0 + wwu * 32 + 16 + rr) * K + k0 + cc,  As + wwu * 1024 + 512);
    gld16(Bt + (size_t)(n0 + wwu * 32 + rr) * K + k0 + cc,      Bs + wwu * 1024);
    gld16(Bt + (size_t)(n0 + wwu * 32 + 16 + rr) * K + k0 + cc, Bs + wwu * 1024 + 512);
    __syncthreads();
    bf16x8 af[4], bfr[4];
#pragma unroll
    for (int i = 0; i < 4; i++) {
      af[i]  = *(const bf16x8*)(As + (wm + i * 16 + l15) * 32 + quad * 8);
      bfr[i] = *(const bf16x8*)(Bs + (wn + i * 16 + l15) * 32 + quad * 8);
    }
#pragma unroll
    for (int i = 0; i < 4; i++)
#pragma unroll
      for (int j = 0; j < 4; j++)
        acc[i][j] = __builtin_amdgcn_mfma_f32_16x16x32_bf16(af[i], bfr[j], acc[i][j], 0, 0, 0);
  }
}

// ---------------- QKV projection ----------------
// Grid: (m-panel FASTEST, n-panel, which) -> XCD d keeps A-slice (m%8==d) L2-resident
// across all (n,which) phases; only B (6.3MB) is multicast across XCDs.
// Q: row-major [bh][s][d], scaled by log2e.
// K, V: FRAGMENT-MAJOR: [bh][T=s/64][slot 0..7][lane 0..63][j 0..7] (slot = 1KB), exactly
// the MFMA fragments k_attn consumes -> attention reads lane-linear 16B/lane.
__global__ __launch_bounds__(256) void k_gemm_qkv(
    const bf16_t* __restrict__ A, const bf16_t* __restrict__ Wqt,
    const bf16_t* __restrict__ Wkt, const bf16_t* __restrict__ Wvt,
    bf16_t* __restrict__ Q, bf16_t* __restrict__ Kf, bf16_t* __restrict__ Vf) {
  __shared__ bf16_t As[128 * 32];
  __shared__ bf16_t Bs[128 * 32];
  const int which = blockIdx.z;
  const bf16_t* Bt = which == 0 ? Wqt : (which == 1 ? Wkt : Wvt);
  const int m0 = blockIdx.x * 128, n0 = blockIdx.y * 128;
  f32x4 acc[4][4];
  gemm_tile(A, Bt, DM, m0, n0, As, Bs, acc);

  const int tid = threadIdx.x;
  const int lane = tid & 63, wave = tid >> 6;
  const int l15 = lane & 15, quad = lane >> 4;
  const int wm = (wave >> 1) * 64, wn = (wave & 1) * 64;

  if (which == 0) {
#pragma unroll
    for (int i = 0; i < 4; i++)
#pragma unroll
      for (int j = 0; j < 4; j++)
#pragma unroll
        for (int r = 0; r < 4; r++) {
          int m = m0 + wm + i * 16 + quad * 4 + r;
          int n = n0 + wn + j * 16 + l15;
          int b = m >> 11, s = m & (SS - 1);
          int h = n >> 6, d = n & 63;
          Q[(((size_t)(b * NH + h)) * SS + s) * DK + d] = (bf16_t)(acc[i][j][r] * LOG2E);
        }
  } else if (which == 1) {
#pragma unroll
    for (int i = 0; i < 4; i++)
#pragma unroll
      for (int j = 0; j < 4; j++)
#pragma unroll
        for (int r = 0; r < 4; r++) {
          int m = m0 + wm + i * 16 + quad * 4 + r;
          int n = n0 + wn + j * 16 + l15;
          int b = m >> 11, s = m & (SS - 1);
          int h = n >> 6, d = n & 63;
          int slot = 4 * ((s >> 5) & 1) + 2 * ((s >> 2) & 1) + (d >> 5);
          int fl = ((d >> 3) & 3) * 16 + 4 * ((s >> 3) & 3) + (s & 3);
          Kf[(((size_t)(b * NH + h) * 32 + (s >> 6)) * 8 + slot) * 512 + fl * 8 + (d & 7)] =
              (bf16_t)acc[i][j][r];
        }
  } else {
#pragma unroll
    for (int i = 0; i < 4; i++)
#pragma unroll
      for (int j = 0; j < 4; j++) {
        int m = m0 + wm + i * 16 + quad * 4;   // 4 consecutive s, 4-aligned
        int n = n0 + wn + j * 16 + l15;
        int b = m >> 11, s = m & (SS - 1);
        int h = n >> 6, d = n & 63;
        int slot = 4 * ((s >> 5) & 1) + (d >> 4);
        int fl = ((s >> 3) & 3) * 16 + (d & 15);
        bf16x4 pk = {(bf16_t)acc[i][j][0], (bf16_t)acc[i][j][1],
                     (bf16_t)acc[i][j][2], (bf16_t)acc[i][j][3]};
        *(bf16x4*)(&Vf[(((size_t)(b * NH + h) * 32 + (s >> 6)) * 8 + slot) * 512 +
                       fl * 8 + (s & 7)]) = pk;
      }
  }
}

// ---------------- flash attention: barrier-free loop, direct fragment loads ---------------
// (unchanged from R6: wave (qh,kh) owns 64 q-rows x 32 keys/tile; K/V fragment streams
// global->VGPR register-double-buffered; bias saturated-constant except 6/32 band iters)
__global__ __launch_bounds__(256, 2) void k_attn(const bf16_t* __restrict__ Qg,
                                                 const bf16_t* __restrict__ Kf,
                                                 const bf16_t* __restrict__ Vf,
                                                 const float* __restrict__ biasT,
                                                 bf16_t* __restrict__ ctx) {
  const int bh = blockIdx.y;
  const int b = bh >> 4, h = bh & 15;
  const int it0 = blockIdx.x * 128;
  const bf16_t* Qp = Qg + ((size_t)bh * SS + it0) * DK;
  const float* biasH = biasT + h * (2 * SS - 1);

  __shared__ float bias2[512][2];         // diag-band: bias2[w] = {B(w-256), B(w-255)}
  __shared__ float OsumS[2][4][16];       // per (qh, mi, qrow) partial denominators
  __shared__ f32x4 Ored[2 * 4 * 4 * 64];  // 32 KB cross-wave O partials

  const int tid = threadIdx.x;
  const int lane = tid & 63, wave = tid >> 6;
  const int l15 = lane & 15, quad = lane >> 4;
  const int kh = wave & 1, qh = wave >> 1;

  for (int w = tid; w < 512; w += 256) {
    int g = w - 256 + (SS - 1);
    bias2[w][0] = biasH[g];
    bias2[w][1] = biasH[g + 1];
  }
  const float Bpos = biasH[(SS - 1) + 1024];   // rel >= 128: saturated bucket 31
  const float Bneg = biasH[(SS - 1) - 1024];   // rel <= -128: saturated bucket 15

  const bf16_t* KfB = Kf + (size_t)bh * 32 * 4096 + lane * 8;
  const bf16_t* VfB = Vf + (size_t)bh * 32 * 4096 + lane * 8;
  auto loadfrag = [&](int it, bf16x8 (&kf)[2][2], bf16x8 (&vf)[4]) {
    const bf16_t* kb = KfB + (size_t)it * 4096;
#pragma unroll
    for (int t = 0; t < 2; t++)
#pragma unroll
      for (int hf = 0; hf < 2; hf++)
        kf[t][hf] = *(const bf16x8*)(kb + ((2 * kh + t) * 2 + hf) * 512);
    const bf16_t* vb = VfB + (size_t)it * 4096;
#pragma unroll
    for (int ni = 0; ni < 4; ni++)
      vf[ni] = *(const bf16x8*)(vb + (kh * 4 + ni) * 512);
  };

  bf16x8 qf[4][2];
#pragma unroll
  for (int mi = 0; mi < 4; mi++) {
    const bf16_t* qr = Qp + (size_t)(64 * qh + mi * 16 + l15) * DK + quad * 8;
    qf[mi][0] = *(const bf16x8*)qr;
    qf[mi][1] = *(const bf16x8*)(qr + 32);
  }

  f32x4 accO[4][4], accS[4];
  const f32x4 z4 = {0.f, 0.f, 0.f, 0.f};
#pragma unroll
  for (int mi = 0; mi < 4; mi++) {
    accS[mi] = z4;
#pragma unroll
    for (int ni = 0; ni < 4; ni++) accO[mi][ni] = z4;
  }
  const bf16_t one = (bf16_t)1.0f;
  const bf16x8 ones = {one, one, one, one, one, one, one, one};

  const int wb0 = 32 * kh + 8 * quad - 64 * qh - l15 - it0 + 256;

  auto body = [&](int it, bf16x8 (&kf)[2][2], bf16x8 (&vf)[4]) {
    const int diff = it * 64 - it0;
    const bool band = (diff >= -128) && (diff < 256);
    const float cconst = diff >= 256 ? Bpos : Bneg;
    const f32x4 csplat = {cconst, cconst, cconst, cconst};
    const int jb = it * 64 + wb0;
#pragma unroll
    for (int mi = 0; mi < 4; mi++) {
      f32x4 c0, c1;
      if (band) {
        const int w = jb - mi * 16;
        float2 a0 = *(const float2*)bias2[w],     b0 = *(const float2*)bias2[w + 2];
        float2 a1 = *(const float2*)bias2[w + 4], b1 = *(const float2*)bias2[w + 6];
        c0 = f32x4{a0.x, a0.y, b0.x, b0.y};
        c1 = f32x4{a1.x, a1.y, b1.x, b1.y};
      } else {
        c0 = csplat;
        c1 = csplat;
      }
      f32x4 s0 = __builtin_amdgcn_mfma_f32_16x16x32_bf16(
          kf[0][1], qf[mi][1],
          __builtin_amdgcn_mfma_f32_16x16x32_bf16(kf[0][0], qf[mi][0], c0, 0, 0, 0), 0, 0, 0);
      f32x4 s1 = __builtin_amdgcn_mfma_f32_16x16x32_bf16(
          kf[1][1], qf[mi][1],
          __builtin_amdgcn_mfma_f32_16x16x32_bf16(kf[1][0], qf[mi][0], c1, 0, 0, 0), 0, 0, 0);
      bf16x8 pf = {(bf16_t)__builtin_amdgcn_exp2f(s0[0]), (bf16_t)__builtin_amdgcn_exp2f(s0[1]),
                   (bf16_t)__builtin_amdgcn_exp2f(s0[2]), (bf16_t)__builtin_amdgcn_exp2f(s0[3]),
                   (bf16_t)__builtin_amdgcn_exp2f(s1[0]), (bf16_t)__builtin_amdgcn_exp2f(s1[1]),
                   (bf16_t)__builtin_amdgcn_exp2f(s1[2]), (bf16_t)__builtin_amdgcn_exp2f(s1[3])};
#pragma unroll
      for (int ni = 0; ni < 4; ni++)
        accO[mi][ni] = __builtin_amdgcn_mfma_f32_16x16x32_bf16(vf[ni], pf, accO[mi][ni], 0, 0, 0);
      accS[mi] = __builtin_amdgcn_mfma_f32_16x16x32_bf16(ones, pf, accS[mi], 0, 0, 0);
    }
  };

  bf16x8 kfA[2][2], vfA[4], kfB[2][2], vfB[4];
  loadfrag(0, kfA, vfA);
  __syncthreads();  // bias2 ready

  for (int it = 0; it < 32; it += 2) {
    loadfrag(it + 1, kfB, vfB);
    body(it, kfA, vfA);
    if (it + 2 < 32) loadfrag(it + 2, kfA, vfA);
    body(it + 1, kfB, vfB);
  }

  __syncthreads();
  if (kh) {
#pragma unroll
    for (int mi = 0; mi < 4; mi++) {
#pragma unroll
      for (int ni = 0; ni < 4; ni++)
        Ored[((qh * 4 + mi) * 4 + ni) * 64 + lane] = accO[mi][ni];
      if (quad == 0) OsumS[qh][mi][l15] = accS[mi][0];
    }
  }
  __syncthreads();
  if (!kh) {
#pragma unroll
    for (int mi = 0; mi < 4; mi++) {
      float l = accS[mi][0] + OsumS[qh][mi][l15];
      float inv = 1.0f / l;
      int srow = it0 + 64 * qh + mi * 16 + l15;
#pragma unroll
      for (int ni = 0; ni < 4; ni++) {
        f32x4 o = accO[mi][ni] + Ored[((qh * 4 + mi) * 4 + ni) * 64 + lane];
        bf16x4 pk = {(bf16_t)(o[0] * inv), (bf16_t)(o[1] * inv),
                     (bf16_t)(o[2] * inv), (bf16_t)(o[3] * inv)};
        *(bf16x4*)(&ctx[((size_t)(b * SS + srow)) * DM + h * DK + ni * 16 + quad * 4]) = pk;
      }
    }
  }
}

// ---------------- output projection: out = ctx @ Wo (fp32 out), m-panel-fastest grid ------
__global__ __launch_bounds__(256) void k_gemm_out(const bf16_t* __restrict__ A,
                                                  const bf16_t* __restrict__ Wot,
                                                  float* __restrict__ out) {
  __shared__ bf16_t As[128 * 32];
  __shared__ bf16_t Bs[128 * 32];
  const int m0 = blockIdx.x * 128, n0 = blockIdx.y * 128;
  f32x4 acc[4][4];
  gemm_tile(A, Wot, DM, m0, n0, As, Bs, acc);

  const int tid = threadIdx.x;
  const int lane = tid & 63, wave = tid >> 6;
  const int l15 = lane & 15, quad = lane >> 4;
  const int wm = (wave >> 1) * 64, wn = (wave & 1) * 64;
#pragma unroll
  for (int i = 0; i < 4; i++)
#pragma unroll
    for (int j = 0; j < 4; j++)
#pragma unroll
      for (int r = 0; r < 4; r++) {
        int m = m0 + wm + i * 16 + quad * 4 + r;
        int n = n0 + wn + j * 16 + l15;
        out[(size_t)m * DM + n] = acc[i][j][r];
      }
}

extern "C" void kernel_launch(void* const* d_in, const int* in_sizes, int n_in,
                              void* d_out, int out_size, void* d_ws, size_t ws_size,
                              hipStream_t stream) {
  (void)in_sizes; (void)n_in; (void)out_size; (void)ws_size;
  const float* H  = (const float*)d_in[0];
  const float* Wq = (const float*)d_in[1];
  const float* Wk = (const float*)d_in[2];
  const float* Wv = (const float*)d_in[3];
  const float* Wo = (const float*)d_in[4];
  const float* rel = (const float*)d_in[5];
  float* out = (float*)d_out;

  char* w = (char*)d_ws;
  bf16_t* Hbf = (bf16_t*)w; w += (size_t)MM * DM * 2;
  bf16_t* Wqt = (bf16_t*)w; w += (size_t)DM * DM * 2;
  bf16_t* Wkt = (bf16_t*)w; w += (size_t)DM * DM * 2;
  bf16_t* Wvt = (bf16_t*)w; w += (size_t)DM * DM * 2;
  bf16_t* Wot = (bf16_t*)w; w += (size_t)DM * DM * 2;
  bf16_t* Q   = (bf16_t*)w; w += (size_t)MM * DM * 2;
  bf16_t* Kf  = (bf16_t*)w; w += (size_t)MM * DM * 2;
  bf16_t* Vf  = (bf16_t*)w; w += (size_t)MM * DM * 2;
  bf16_t* CTX = (bf16_t*)w; w += (size_t)MM * DM * 2;
  float* biasT = (float*)w;  // NH * 4095 floats

  k_prep<<<9232, 256, 0, stream>>>(H, Hbf, Wq, Wk, Wv, Wo, Wqt, Wkt, Wvt, Wot, rel, biasT);
  k_gemm_qkv<<<dim3(MM / 128, DM / 128, 3), 256, 0, stream>>>(Hbf, Wqt, Wkt, Wvt, Q, Kf, Vf);
  k_attn<<<dim3(SS / 128, NB * NH), 256, 0, stream>>>(Q, Kf, Vf, biasT, CTX);
  k_gemm_out<<<dim3(MM / 128, DM / 128), 256, 0, stream>>>(CTX, Wot, out);
}